// Round 1
// baseline (333.896 us; speedup 1.0000x reference)
//
#include <hip/hip_runtime.h>

#define B_ 8
#define C_ 256
#define N_ 4096
#define NH_ 8
#define HD_ 32

#define ALPHA_ 0.36787944117144233f   // elu(-1)+1 = e^-1
#define BETAS_ (2.0f - ALPHA_)        // k/q spike value 2.0 = ALPHA_ + BETAS_
#define SCALE_ 0.17677669529663687f   // 32^-0.5

// ---------------------------------------------------------------------------
// K1/K4: tiled fp32 GEMM  out[o,n] = sum_i W[o,i] * X[b,i,n]
// Tile: 128(o) x 128(n) x 32(k), 256 threads, 8x8 micro-tile.
// MODE 0: QKV conv + LIF epilogue (blockIdx.z = b*3 + conv)
// MODE 1: plain store (blockIdx.z = b)
// ---------------------------------------------------------------------------
template<int MODE>
__global__ __launch_bounds__(256) void gemm_k(
    const float* __restrict__ Xall,
    const float* __restrict__ W0, const float* __restrict__ W1, const float* __restrict__ W2,
    const float* __restrict__ m0, const float* __restrict__ m1, const float* __restrict__ m2,
    float* __restrict__ o0p, float* __restrict__ o1p, float* __restrict__ o2p)
{
    int b, conv;
    if (MODE == 0) { b = blockIdx.z / 3; conv = blockIdx.z % 3; }
    else           { b = blockIdx.z;     conv = 0; }
    const float* W   = (conv == 0) ? W0 : (conv == 1 ? W1 : W2);
    const float* mem = (conv == 0) ? m0 : (conv == 1 ? m1 : m2);
    float*       out = (conv == 0) ? o0p : (conv == 1 ? o1p : o2p);
    const float* Xb = Xall + (size_t)b * C_ * N_;

    int oT = blockIdx.y * 128;
    int nT = blockIdx.x * 128;

    __shared__ float Ws[32][132];   // [k][o], padded (132*4 B = 33*16 -> float4-aligned rows)
    __shared__ float Xs[32][132];   // [k][n]

    int t  = threadIdx.x;
    int tx = t & 15;        // n-group
    int ty = t >> 4;        // o-group

    float acc[8][8];
    #pragma unroll
    for (int i = 0; i < 8; ++i)
        #pragma unroll
        for (int j = 0; j < 8; ++j) acc[i][j] = 0.0f;

    for (int k0 = 0; k0 < C_; k0 += 32) {
        // stage W tile: rows oT..oT+127, cols k0..k0+31 -> Ws[k][o] (transposed)
        {
            int r = t >> 1;            // 0..127
            int c = (t & 1) * 16;      // 0 or 16
            const float4* src = reinterpret_cast<const float4*>(&W[(size_t)(oT + r) * C_ + k0 + c]);
            #pragma unroll
            for (int q = 0; q < 4; ++q) {
                float4 w4 = src[q];
                Ws[c + q*4 + 0][r] = w4.x;
                Ws[c + q*4 + 1][r] = w4.y;
                Ws[c + q*4 + 2][r] = w4.z;
                Ws[c + q*4 + 3][r] = w4.w;
            }
        }
        // stage X tile: rows k0..k0+31, cols nT..nT+127 -> Xs[k][n]
        {
            int kk = t >> 3;           // 0..31
            int c  = (t & 7) * 16;     // 0..112
            const float4* src = reinterpret_cast<const float4*>(&Xb[(size_t)(k0 + kk) * N_ + nT + c]);
            #pragma unroll
            for (int q = 0; q < 4; ++q)
                *reinterpret_cast<float4*>(&Xs[kk][c + q*4]) = src[q];
        }
        __syncthreads();
        #pragma unroll
        for (int kk = 0; kk < 32; ++kk) {
            float a[8], bb[8];
            *reinterpret_cast<float4*>(&a[0])  = *reinterpret_cast<const float4*>(&Ws[kk][ty*8]);
            *reinterpret_cast<float4*>(&a[4])  = *reinterpret_cast<const float4*>(&Ws[kk][ty*8+4]);
            *reinterpret_cast<float4*>(&bb[0]) = *reinterpret_cast<const float4*>(&Xs[kk][tx*8]);
            *reinterpret_cast<float4*>(&bb[4]) = *reinterpret_cast<const float4*>(&Xs[kk][tx*8+4]);
            #pragma unroll
            for (int i = 0; i < 8; ++i)
                #pragma unroll
                for (int j = 0; j < 8; ++j)
                    acc[i][j] += a[i] * bb[j];
        }
        __syncthreads();
    }

    #pragma unroll
    for (int i = 0; i < 8; ++i) {
        int o = oT + ty*8 + i;
        size_t base = ((size_t)b * C_ + o) * N_ + nT + tx*8;
        if (MODE == 0) {
            #pragma unroll
            for (int half = 0; half < 2; ++half) {
                float4 m4 = *reinterpret_cast<const float4*>(&mem[base + half*4]);
                float4 r4;
                // snntorch Leaky, reset-by-subtraction from detached previous mem
                r4.x = 0.5f*m4.x + acc[i][half*4+0] - (m4.x > 1.0f ? 1.0f : 0.0f);
                r4.y = 0.5f*m4.y + acc[i][half*4+1] - (m4.y > 1.0f ? 1.0f : 0.0f);
                r4.z = 0.5f*m4.z + acc[i][half*4+2] - (m4.z > 1.0f ? 1.0f : 0.0f);
                r4.w = 0.5f*m4.w + acc[i][half*4+3] - (m4.w > 1.0f ? 1.0f : 0.0f);
                *reinterpret_cast<float4*>(&out[base + half*4]) = r4;
            }
        } else {
            *reinterpret_cast<float4*>(&out[base])     = make_float4(acc[i][0], acc[i][1], acc[i][2], acc[i][3]);
            *reinterpret_cast<float4*>(&out[base + 4]) = make_float4(acc[i][4], acc[i][5], acc[i][6], acc[i][7]);
        }
    }
}

// ---------------------------------------------------------------------------
// K2: kv[d,e] = sum_n k[n,d]*v[n,e],  ksum[d] = sum_n k[n,d]  per (b,h)
// k = ALPHA + BETAS*s_k (s = mem_new > 1), v = 2*s_v - 1.
// Exact via 64-bit ballot masks + popcount (bit<->n mapping is arbitrary but
// consistent between k and v; only full sums over n are needed).
// ---------------------------------------------------------------------------
__global__ __launch_bounds__(256) void kv_kernel(
    const float* __restrict__ Km, const float* __restrict__ Vm,
    float* __restrict__ kvp, float* __restrict__ ksump)
{
    int bh = blockIdx.x;            // 0..63
    int b = bh >> 3, h = bh & 7;
    const float* Kp = Km + ((size_t)(b * C_ + h * HD_)) * N_;
    const float* Vp = Vm + ((size_t)(b * C_ + h * HD_)) * N_;

    __shared__ unsigned long long mk[32][65];   // pad to dodge bank conflicts
    __shared__ unsigned long long mv[32][65];
    __shared__ float cntk[32], cntv[32];

    int t = threadIdx.x;
    int wave = t >> 6, lane = t & 63;

    for (int r = wave; r < 32; r += 4) {
        const float* kr = Kp + (size_t)r * N_;
        const float* vr = Vp + (size_t)r * N_;
        for (int w4 = 0; w4 < 16; ++w4) {
            float4 kf = *reinterpret_cast<const float4*>(&kr[w4 * 256 + lane * 4]);
            float4 vf = *reinterpret_cast<const float4*>(&vr[w4 * 256 + lane * 4]);
            unsigned long long k0 = __ballot(kf.x > 1.0f);
            unsigned long long k1 = __ballot(kf.y > 1.0f);
            unsigned long long k2 = __ballot(kf.z > 1.0f);
            unsigned long long k3 = __ballot(kf.w > 1.0f);
            unsigned long long v0 = __ballot(vf.x > 1.0f);
            unsigned long long v1 = __ballot(vf.y > 1.0f);
            unsigned long long v2 = __ballot(vf.z > 1.0f);
            unsigned long long v3 = __ballot(vf.w > 1.0f);
            if (lane == 0) {
                mk[r][w4*4+0] = k0; mk[r][w4*4+1] = k1; mk[r][w4*4+2] = k2; mk[r][w4*4+3] = k3;
                mv[r][w4*4+0] = v0; mv[r][w4*4+1] = v1; mv[r][w4*4+2] = v2; mv[r][w4*4+3] = v3;
            }
        }
    }
    __syncthreads();

    if (t < 32) {
        int c = 0;
        for (int w = 0; w < 64; ++w) c += __popcll(mk[t][w]);
        cntk[t] = (float)c;
    } else if (t < 64) {
        int d = t - 32, c = 0;
        for (int w = 0; w < 64; ++w) c += __popcll(mv[d][w]);
        cntv[d] = (float)c;
    }
    __syncthreads();

    int d  = t >> 3;
    int e0 = (t & 7) * 4;
    #pragma unroll
    for (int j = 0; j < 4; ++j) {
        int e = e0 + j;
        int P = 0;
        for (int w = 0; w < 64; ++w) P += __popcll(mk[d][w] & mv[e][w]);
        float skv = 2.0f * (float)P - cntk[d];          // sum_n s_k * v
        float sv  = 2.0f * cntv[e] - 4096.0f;           // sum_n v
        kvp[(size_t)bh * 1024 + d * 32 + e] = ALPHA_ * sv + BETAS_ * skv;
    }
    if ((t & 7) == 0)
        ksump[bh * 32 + d] = ALPHA_ * 4096.0f + BETAS_ * cntk[d];
}

// ---------------------------------------------------------------------------
// K3: att[b, h*32+e, n] = SCALE * (sum_d q[n,d]*kv[d,e]) / (sum_d q[n,d]*ksum[d] + 1e-6)
// One n per lane; q staged in LDS; kv/ksum are block-uniform -> scalar loads.
// ---------------------------------------------------------------------------
__global__ __launch_bounds__(256) void att_kernel(
    const float* __restrict__ Qm, const float* __restrict__ kvp,
    const float* __restrict__ ksump, float* __restrict__ att)
{
    int bh = blockIdx.y; int b = bh >> 3, h = bh & 7;
    int n0 = blockIdx.x * 256;
    const float* Qp = Qm + ((size_t)(b * C_ + h * HD_)) * N_;

    __shared__ float qs[32][260];

    int t = threadIdx.x;
    {
        int r  = t >> 3;            // 0..31
        int c0 = (t & 7) * 32;      // 0..224
        #pragma unroll
        for (int q4 = 0; q4 < 8; ++q4) {
            float4 v = *reinterpret_cast<const float4*>(&Qp[(size_t)r * N_ + n0 + c0 + q4 * 4]);
            qs[r][c0 + q4*4 + 0] = (v.x > 1.0f) ? 2.0f : ALPHA_;
            qs[r][c0 + q4*4 + 1] = (v.y > 1.0f) ? 2.0f : ALPHA_;
            qs[r][c0 + q4*4 + 2] = (v.z > 1.0f) ? 2.0f : ALPHA_;
            qs[r][c0 + q4*4 + 3] = (v.w > 1.0f) ? 2.0f : ALPHA_;
        }
    }
    __syncthreads();

    float q[32];
    #pragma unroll
    for (int d2 = 0; d2 < 32; ++d2) q[d2] = qs[d2][t];

    const float* ksb = ksump + bh * 32;
    float den = 1e-6f;
    #pragma unroll
    for (int d2 = 0; d2 < 32; ++d2) den += q[d2] * ksb[d2];
    float rden = SCALE_ / den;

    const float* kvb = kvp + (size_t)bh * 1024;
    for (int e = 0; e < 32; ++e) {
        float num = 0.0f;
        #pragma unroll
        for (int d2 = 0; d2 < 32; ++d2) num += q[d2] * kvb[d2 * 32 + e];
        att[((size_t)b * C_ + h * HD_ + e) * N_ + n0 + t] = num * rden;
    }
}

// ---------------------------------------------------------------------------
// K5: BatchNorm batch stats per channel (biased var), fp64 accumulation.
// ---------------------------------------------------------------------------
__global__ __launch_bounds__(256) void bn_stats(
    const float* __restrict__ out2, float* __restrict__ stats)
{
    int o = blockIdx.x;
    int t = threadIdx.x;
    double s = 0.0, ss = 0.0;
    for (int b = 0; b < B_; ++b) {
        const float* p = out2 + ((size_t)b * C_ + o) * N_;
        for (int i = t * 4; i < N_; i += 1024) {
            float4 v = *reinterpret_cast<const float4*>(&p[i]);
            s  += (double)v.x + (double)v.y + (double)v.z + (double)v.w;
            ss += (double)v.x * v.x + (double)v.y * v.y + (double)v.z * v.z + (double)v.w * v.w;
        }
    }
    __shared__ double rs[256], rss[256];
    rs[t] = s; rss[t] = ss;
    __syncthreads();
    for (int st = 128; st > 0; st >>= 1) {
        if (t < st) { rs[t] += rs[t + st]; rss[t] += rss[t + st]; }
        __syncthreads();
    }
    if (t == 0) {
        double mean = rs[0] / 32768.0;
        double var  = rss[0] / 32768.0 - mean * mean;
        stats[o * 2 + 0] = (float)mean;
        stats[o * 2 + 1] = (float)(1.0 / sqrt(var + 1e-5));
    }
}

// K6: in-place BN apply: y = (x - mean)*rstd*gamma + beta
__global__ __launch_bounds__(256) void bn_apply(
    float* __restrict__ out, const float* __restrict__ stats,
    const float* __restrict__ gamma, const float* __restrict__ beta)
{
    size_t i = ((size_t)blockIdx.x * 256 + threadIdx.x) * 4;
    int o = (int)((i >> 12) & 255);
    float m = stats[o * 2], r = stats[o * 2 + 1];
    float g = gamma[o] * r;
    float c = beta[o] - m * g;
    float4 v = *reinterpret_cast<float4*>(&out[i]);
    v.x = v.x * g + c;
    v.y = v.y * g + c;
    v.z = v.z * g + c;
    v.w = v.w * g + c;
    *reinterpret_cast<float4*>(&out[i]) = v;
}

// ---------------------------------------------------------------------------
extern "C" void kernel_launch(void* const* d_in, const int* in_sizes, int n_in,
                              void* d_out, int out_size, void* d_ws, size_t ws_size,
                              hipStream_t stream)
{
    (void)in_sizes; (void)n_in; (void)out_size; (void)ws_size;

    const float* x     = (const float*)d_in[0];
    const float* qmem  = (const float*)d_in[1];
    const float* kmem  = (const float*)d_in[2];
    const float* vmem  = (const float*)d_in[3];
    const float* Wq    = (const float*)d_in[4];
    const float* Wk    = (const float*)d_in[5];
    const float* Wv    = (const float*)d_in[6];
    const float* Wo    = (const float*)d_in[7];
    const float* gamma = (const float*)d_in[8];
    const float* beta  = (const float*)d_in[9];

    const size_t TSZ = (size_t)B_ * C_ * N_;     // 8,388,608 elements per tensor
    float* out0 = (float*)d_out;                 // final BN output
    float* outq = out0 + TSZ;                    // q_mem_n
    float* outk = outq + TSZ;                    // k_mem_n
    float* outv = outk + TSZ;                    // v_mem_n

    float* att   = (float*)d_ws;                 // [B][C][N]  (32 MiB)
    float* kvp   = att + TSZ;                    // [64][32][32]
    float* ksump = kvp + 64 * 1024;              // [64][32]
    float* stats = ksump + 64 * 32;              // [256][2]

    dim3 blk(256);

    // K1: Q,K,V conv + LIF -> mem outputs
    gemm_k<0><<<dim3(32, 2, 24), blk, 0, stream>>>(
        x, Wq, Wk, Wv, qmem, kmem, vmem, outq, outk, outv);

    // K2: kv + ksum per (b,h)
    kv_kernel<<<dim3(64), blk, 0, stream>>>(outk, outv, kvp, ksump);

    // K3: attention -> att (channel-major) in workspace
    att_kernel<<<dim3(16, 64), blk, 0, stream>>>(outq, kvp, ksump, att);

    // K4: Wo conv: att -> out0
    gemm_k<1><<<dim3(32, 2, 8), blk, 0, stream>>>(
        att, Wo, nullptr, nullptr, nullptr, nullptr, nullptr, out0, nullptr, nullptr);

    // K5/K6: BatchNorm
    bn_stats<<<dim3(256), blk, 0, stream>>>(out0, stats);
    bn_apply<<<dim3(8192), blk, 0, stream>>>(out0, stats, gamma, beta);
}